// Round 9
// baseline (116.218 us; speedup 1.0000x reference)
//
#include <hip/hip_runtime.h>
#include <stdint.h>

#define NROWS 384
#define DDIM  768
#define NCOL  1536
#define L2E2  2.885390081777927f   // 2*log2(e): exp(2s) = exp2(L2E2*s)

// ws regions (float-slot offsets):
//   A2   [384 i][768 d]  fp32 at 0        (prescaled (A+b1)*L2E2, row-major)
//   Bt2  [192 dg][384 j][4] fp32 at 294912 (prescaled B*L2E2, d-blocked)
//   pbf  [384 i][768 k]  bf16 at 589824   (p converted once)
//   wbf  [768 o][1536 c] bf16 at 737280   (W1 converted once)
#define WS_BT  294912
#define WS_PBF 589824
#define WS_WBF 737280

typedef short bf16x8 __attribute__((ext_vector_type(8)));
typedef float f32x4  __attribute__((ext_vector_type(4)));

__device__ __forceinline__ uint16_t f2bf(float x) {  // RNE float->bf16
  const uint32_t u = __float_as_uint(x);
  return (uint16_t)((u + 0x7FFFu + ((u >> 16) & 1u)) >> 16);
}
__device__ __forceinline__ bf16x8 pack8(const float* f) {
  bf16x8 r;
  #pragma unroll
  for (int j = 0; j < 8; ++j) r[j] = (short)f2bf(f[j]);
  return r;
}

// ---------------------------------------------------------------------------
// K0: one-time fp32->bf16 conversion of p and W1 (layouts preserved).
// ---------------------------------------------------------------------------
__global__ __launch_bounds__(256) void k0_cvt(
    const float* __restrict__ p, const float* __restrict__ W1,
    float* __restrict__ ws) {
  const int t = blockIdx.x * 256 + threadIdx.x;
  const int NP = NROWS * DDIM / 8;          // 36864 p-tasks
  float f[8];
  if (t < NP) {
    *(float4*)&f[0] = *(const float4*)&p[t * 8];
    *(float4*)&f[4] = *(const float4*)&p[t * 8 + 4];
    *(bf16x8*)((uint16_t*)(ws + WS_PBF) + (size_t)t * 8) = pack8(f);
  } else {
    const int u = t - NP;                   // 147456 W1-tasks
    *(float4*)&f[0] = *(const float4*)&W1[(size_t)u * 8];
    *(float4*)&f[4] = *(const float4*)&W1[(size_t)u * 8 + 4];
    *(bf16x8*)((uint16_t*)(ws + WS_WBF) + (size_t)u * 8) = pack8(f);
  }
}

// ---------------------------------------------------------------------------
// K1: C[i][o] = sum_k p[i][k] * W1[o%768][(o>=768)*768 + k], MFMA bf16.
// bf16 fragments loaded directly (16B, L2-resident). Block = 4 waves =
// 2 n-subtiles x 2 k-halves (LDS combine). Per wave: TWO independent MFMA
// accumulator chains (even/odd 32-k pairs), fully unrolled -> 12 loads in
// flight, MFMA dep-chain halved. Grid 48x24 = 1152 blocks = 4.5 waves/SIMD.
// ---------------------------------------------------------------------------
__global__ __launch_bounds__(256) void k1_mfma(
    const float* __restrict__ b1, float* __restrict__ ws) {
  __shared__ float cmb[2][64][4];

  const int lane = threadIdx.x & 63;
  const int w    = threadIdx.x >> 6;
  const int nsub = w & 1;
  const int ksub = w >> 1;
  const int nn   = lane & 15;
  const int quad = lane >> 4;

  const int mbase = blockIdx.y * 16;
  const int nbase = blockIdx.x * 32 + nsub * 16;   // [0,1536)
  const int g     = nbase >= DDIM;
  const int obase = nbase - g * DDIM;              // W1 row base [0,768)

  const uint16_t* __restrict__ pa =
      (const uint16_t*)(ws + WS_PBF) + (size_t)(mbase + nn) * DDIM + ksub * 384 + quad * 8;
  const uint16_t* __restrict__ pb =
      (const uint16_t*)(ws + WS_WBF) + (size_t)(obase + nn) * NCOL + g * DDIM + ksub * 384 + quad * 8;

  f32x4 acc0 = {0.f, 0.f, 0.f, 0.f};
  f32x4 acc1 = {0.f, 0.f, 0.f, 0.f};

  #pragma unroll
  for (int kk = 0; kk < 384; kk += 64) {
    const bf16x8 a0 = *(const bf16x8*)&pa[kk];
    const bf16x8 b0 = *(const bf16x8*)&pb[kk];
    const bf16x8 a1 = *(const bf16x8*)&pa[kk + 32];
    const bf16x8 b1v = *(const bf16x8*)&pb[kk + 32];
    acc0 = __builtin_amdgcn_mfma_f32_16x16x32_bf16(a0, b0, acc0, 0, 0, 0);
    acc1 = __builtin_amdgcn_mfma_f32_16x16x32_bf16(a1, b1v, acc1, 0, 0, 0);
  }
  f32x4 acc = acc0 + acc1;

  if (ksub == 1)
    *(float4*)&cmb[nsub][lane][0] = make_float4(acc[0], acc[1], acc[2], acc[3]);
  __syncthreads();
  if (ksub == 0) {
    const float4 o4 = *(const float4*)&cmb[nsub][lane][0];
    float v[4] = {acc[0] + o4.x, acc[1] + o4.y, acc[2] + o4.z, acc[3] + o4.w};
    const int od = obase + nn;
    if (!g) {
      const float bias = b1[od];
      float* __restrict__ A2 = ws;
      #pragma unroll
      for (int r = 0; r < 4; ++r)
        A2[(size_t)(mbase + quad * 4 + r) * DDIM + od] = (v[r] + bias) * L2E2;
    } else {
      float* __restrict__ Bt = ws + WS_BT;
      const int hi = (od >> 2) * NROWS;
      const int lo = od & 3;
      #pragma unroll
      for (int r = 0; r < 4; ++r)
        Bt[(size_t)(hi + mbase + quad * 4 + r) * 4 + lo] = v[r] * L2E2;
    }
  }
}

// ---------------------------------------------------------------------------
// K2: logits[i][j][c] = (sumW_c - 2*sum_d W2[c][d]*r_ijd) + b2[c],
//     r = rcp(exp2(A2[i][d] + Bt2[j][d]) + 1)   (prescale folded in K1)
// Block = 512 thr = 8 waves = 8 d-eighths; wave = 2 i-rows x 128 j (2 j per
// lane: j, j+64) x 96 d. Uniform LDS reads (A-pair + W2, broadcast b128)
// amortized over 16 elements/dg -> LDS pipe time halved vs R8; 32 independent
// exp chains/iter. Eighth-partials combined via LDS. Grid (192,3) = 576
// blocks = 4608 waves = 4.5 waves/SIMD.
// ---------------------------------------------------------------------------
__global__ __launch_bounds__(512) void k2_fused(
    const float* __restrict__ ws, const float* __restrict__ W2,
    const float* __restrict__ b2, float* __restrict__ out) {
  __shared__ float As[192][12];    // [dg][row 0..1][d 0..3], pad to 12
  __shared__ float Wsh[192][12];   // [dg][c 0..1][d 0..3],  pad to 12
  __shared__ float part[7][2][2][64][2];  // [h-1][row][jhalf][lane][class]

  const int tid  = threadIdx.x;
  const int lane = tid & 63;
  const int h    = tid >> 6;            // d-eighth 0..7
  const int i0   = blockIdx.x * 2;
  const int jb   = blockIdx.y * 128;
  const int j    = jb + lane;

  // stage A-row pair + W2 into LDS (coalesced float4 source reads)
  for (int u = tid; u < 768; u += 512) {
    if (u < 384) {
      const int row = u / 192, dg = u % 192;
      *(float4*)&As[dg][row * 4] =
          *(const float4*)&ws[(size_t)(i0 + row) * DDIM + dg * 4];
    } else {
      const int v = u - 384, c = v / 192, dg = v % 192;
      *(float4*)&Wsh[dg][c * 4] =
          *(const float4*)&W2[(size_t)c * DDIM + dg * 4];
    }
  }

  // eighth-range sumW (96 floats; wave-uniform after butterfly)
  const float* __restrict__ w0g = W2 + h * 96;
  const float* __restrict__ w1g = W2 + DDIM + h * 96;
  float sw0 = w0g[lane] + (lane < 32 ? w0g[64 + lane] : 0.f);
  float sw1 = w1g[lane] + (lane < 32 ? w1g[64 + lane] : 0.f);
  #pragma unroll
  for (int off = 32; off; off >>= 1) {
    sw0 += __shfl_xor(sw0, off);
    sw1 += __shfl_xor(sw1, off);
  }
  __syncthreads();

  const float4* __restrict__ B4 =
      (const float4*)(ws + WS_BT) + (size_t)(h * 24) * NROWS;

  f32x4 s[2][2][2] = {};   // [row][jhalf][class]

  #pragma unroll 2
  for (int dg = 0; dg < 24; ++dg) {
    const int dgg = h * 24 + dg;
    const float4 b4a = B4[(size_t)dg * NROWS + j];        // coalesced
    const float4 b4b = B4[(size_t)dg * NROWS + j + 64];   // coalesced
    const float4 av0 = *(const float4*)&As[dgg][0];       // LDS broadcast
    const float4 av1 = *(const float4*)&As[dgg][4];
    const float4 w04 = *(const float4*)&Wsh[dgg][0];
    const float4 w14 = *(const float4*)&Wsh[dgg][4];

    #pragma unroll
    for (int rw = 0; rw < 2; ++rw) {
      const float4 av = rw ? av1 : av0;
      #pragma unroll
      for (int jh = 0; jh < 2; ++jh) {
        const float4 b4 = jh ? b4b : b4a;
        float e, r;
        e = __builtin_amdgcn_exp2f(av.x + b4.x); r = __builtin_amdgcn_rcpf(e + 1.f);
        s[rw][jh][0][0] = fmaf(w04.x, r, s[rw][jh][0][0]);
        s[rw][jh][1][0] = fmaf(w14.x, r, s[rw][jh][1][0]);
        e = __builtin_amdgcn_exp2f(av.y + b4.y); r = __builtin_amdgcn_rcpf(e + 1.f);
        s[rw][jh][0][1] = fmaf(w04.y, r, s[rw][jh][0][1]);
        s[rw][jh][1][1] = fmaf(w14.y, r, s[rw][jh][1][1]);
        e = __builtin_amdgcn_exp2f(av.z + b4.z); r = __builtin_amdgcn_rcpf(e + 1.f);
        s[rw][jh][0][2] = fmaf(w04.z, r, s[rw][jh][0][2]);
        s[rw][jh][1][2] = fmaf(w14.z, r, s[rw][jh][1][2]);
        e = __builtin_amdgcn_exp2f(av.w + b4.w); r = __builtin_amdgcn_rcpf(e + 1.f);
        s[rw][jh][0][3] = fmaf(w04.w, r, s[rw][jh][0][3]);
        s[rw][jh][1][3] = fmaf(w14.w, r, s[rw][jh][1][3]);
      }
    }
  }

  float pl[2][2][2];
  #pragma unroll
  for (int rw = 0; rw < 2; ++rw)
    #pragma unroll
    for (int jh = 0; jh < 2; ++jh) {
      const float S0 = (s[rw][jh][0][0] + s[rw][jh][0][1]) + (s[rw][jh][0][2] + s[rw][jh][0][3]);
      const float S1 = (s[rw][jh][1][0] + s[rw][jh][1][1]) + (s[rw][jh][1][2] + s[rw][jh][1][3]);
      pl[rw][jh][0] = fmaf(-2.f, S0, sw0);
      pl[rw][jh][1] = fmaf(-2.f, S1, sw1);
    }

  if (h) {
    #pragma unroll
    for (int rw = 0; rw < 2; ++rw)
      #pragma unroll
      for (int jh = 0; jh < 2; ++jh) {
        part[h - 1][rw][jh][lane][0] = pl[rw][jh][0];
        part[h - 1][rw][jh][lane][1] = pl[rw][jh][1];
      }
  }
  __syncthreads();
  if (h == 0) {
    #pragma unroll
    for (int rw = 0; rw < 2; ++rw)
      #pragma unroll
      for (int jh = 0; jh < 2; ++jh) {
        float2 r2;
        r2.x = pl[rw][jh][0] + b2[0];
        r2.y = pl[rw][jh][1] + b2[1];
        #pragma unroll
        for (int e = 0; e < 7; ++e) {
          r2.x += part[e][rw][jh][lane][0];
          r2.y += part[e][rw][jh][lane][1];
        }
        *(float2*)&out[((size_t)(i0 + rw) * NROWS + jb + jh * 64 + lane) * 2] = r2;
      }
  }
}

// ---------------------------------------------------------------------------
extern "C" void kernel_launch(void* const* d_in, const int* in_sizes, int n_in,
                              void* d_out, int out_size, void* d_ws, size_t ws_size,
                              hipStream_t stream) {
  const float* p  = (const float*)d_in[0];   // [384, 768]
  const float* W1 = (const float*)d_in[1];   // [768, 1536]
  const float* b1 = (const float*)d_in[2];   // [768]
  const float* W2 = (const float*)d_in[3];   // [2, 768]
  const float* b2 = (const float*)d_in[4];   // [2]
  float* out = (float*)d_out;                // [384, 384, 2]
  float* ws  = (float*)d_ws;                 // ~5.3 MB used

  k0_cvt<<<dim3(720), 256, 0, stream>>>(p, W1, ws);

  dim3 g1(NCOL / 32, NROWS / 16);            // 48 x 24 = 1152 blocks
  k1_mfma<<<g1, 256, 0, stream>>>(b1, ws);

  dim3 g2(NROWS / 2, NROWS / 128);           // 192 x 3 = 576 blocks
  k2_fused<<<g2, 512, 0, stream>>>(ws, W2, b2, out);
}

// Round 11
// 103.118 us; speedup vs baseline: 1.1270x; 1.1270x over previous
//
#include <hip/hip_runtime.h>
#include <stdint.h>

#define NROWS 384
#define DDIM  768
#define NCOL  1536
#define L2E2  2.885390081777927f   // 2*log2(e): exp(2s) = exp2(L2E2*s)

// ws regions (float-slot offsets):
//   EA   [384 i][768 d]  fp32 at 0        (exp2(L2E2*(A+b1)), row-major)
//   EBt  [192 dg][384 j][4] fp32 at 294912 (exp2(L2E2*B), d-blocked)
//   pbf  [384 i][768 k]  bf16 at 589824   (p converted once)
//   wbf  [768 o][1536 c] bf16 at 737280   (W1 converted once)
#define WS_BT  294912
#define WS_PBF 589824
#define WS_WBF 737280

typedef short bf16x8 __attribute__((ext_vector_type(8)));
typedef float f32x4  __attribute__((ext_vector_type(4)));

__device__ __forceinline__ uint16_t f2bf(float x) {  // RNE float->bf16
  const uint32_t u = __float_as_uint(x);
  return (uint16_t)((u + 0x7FFFu + ((u >> 16) & 1u)) >> 16);
}
__device__ __forceinline__ bf16x8 pack8(const float* f) {
  bf16x8 r;
  #pragma unroll
  for (int j = 0; j < 8; ++j) r[j] = (short)f2bf(f[j]);
  return r;
}

// ---------------------------------------------------------------------------
// K0: one-time fp32->bf16 conversion of p and W1 (layouts preserved).
// ---------------------------------------------------------------------------
__global__ __launch_bounds__(256) void k0_cvt(
    const float* __restrict__ p, const float* __restrict__ W1,
    float* __restrict__ ws) {
  const int t = blockIdx.x * 256 + threadIdx.x;
  const int NP = NROWS * DDIM / 8;          // 36864 p-tasks
  float f[8];
  if (t < NP) {
    *(float4*)&f[0] = *(const float4*)&p[t * 8];
    *(float4*)&f[4] = *(const float4*)&p[t * 8 + 4];
    *(bf16x8*)((uint16_t*)(ws + WS_PBF) + (size_t)t * 8) = pack8(f);
  } else {
    const int u = t - NP;                   // 147456 W1-tasks
    *(float4*)&f[0] = *(const float4*)&W1[(size_t)u * 8];
    *(float4*)&f[4] = *(const float4*)&W1[(size_t)u * 8 + 4];
    *(bf16x8*)((uint16_t*)(ws + WS_WBF) + (size_t)u * 8) = pack8(f);
  }
}

// ---------------------------------------------------------------------------
// K1: C[i][o] = sum_k p[i][k] * W1[o%768][(o>=768)*768 + k], MFMA bf16.
// bf16 fragments loaded directly (16B, L2-resident) — no pack VALU.
// Block = 256 thr = 4 waves = 2 n-subtiles x 2 k-halves (LDS combine).
// Grid 48x24 = 1152 blocks. Epilogue folds b1 + L2E2 AND the exp2:
// stores EA = exp2(L2E2*(A+b1)) row-major, EB = exp2(L2E2*B) d-blocked,
// so K2's inner loop needs no transcendental exp (exp(2s)=EA*EB).
// ---------------------------------------------------------------------------
__global__ __launch_bounds__(256) void k1_mfma(
    const float* __restrict__ b1, float* __restrict__ ws) {
  __shared__ float cmb[2][64][4];

  const int lane = threadIdx.x & 63;
  const int w    = threadIdx.x >> 6;
  const int nsub = w & 1;
  const int ksub = w >> 1;
  const int nn   = lane & 15;
  const int quad = lane >> 4;

  const int mbase = blockIdx.y * 16;
  const int nbase = blockIdx.x * 32 + nsub * 16;   // [0,1536)
  const int g     = nbase >= DDIM;
  const int obase = nbase - g * DDIM;              // W1 row base [0,768)

  const uint16_t* __restrict__ pa =
      (const uint16_t*)(ws + WS_PBF) + (size_t)(mbase + nn) * DDIM + ksub * 384 + quad * 8;
  const uint16_t* __restrict__ pb =
      (const uint16_t*)(ws + WS_WBF) + (size_t)(obase + nn) * NCOL + g * DDIM + ksub * 384 + quad * 8;

  f32x4 acc = {0.f, 0.f, 0.f, 0.f};

  #pragma unroll 4
  for (int kk = 0; kk < 384; kk += 32) {
    const bf16x8 a = *(const bf16x8*)&pa[kk];
    const bf16x8 b = *(const bf16x8*)&pb[kk];
    acc = __builtin_amdgcn_mfma_f32_16x16x32_bf16(a, b, acc, 0, 0, 0);
  }

  if (ksub == 1)
    *(float4*)&cmb[nsub][lane][0] = make_float4(acc[0], acc[1], acc[2], acc[3]);
  __syncthreads();
  if (ksub == 0) {
    const float4 o4 = *(const float4*)&cmb[nsub][lane][0];
    float v[4] = {acc[0] + o4.x, acc[1] + o4.y, acc[2] + o4.z, acc[3] + o4.w};
    const int od = obase + nn;
    if (!g) {
      const float bias = b1[od];
      float* __restrict__ A2 = ws;
      #pragma unroll
      for (int r = 0; r < 4; ++r)
        A2[(size_t)(mbase + quad * 4 + r) * DDIM + od] =
            __builtin_amdgcn_exp2f((v[r] + bias) * L2E2);
    } else {
      float* __restrict__ Bt = ws + WS_BT;
      const int hi = (od >> 2) * NROWS;
      const int lo = od & 3;
      #pragma unroll
      for (int r = 0; r < 4; ++r)
        Bt[(size_t)(hi + mbase + quad * 4 + r) * 4 + lo] =
            __builtin_amdgcn_exp2f(v[r] * L2E2);
    }
  }
}

// ---------------------------------------------------------------------------
// K2: logits[i][j][c] = (sumW_c - 2*sum_d W2[c][d]*r_ijd) + b2[c],
//     r = rcp(EA[i][d]*EB[j][d] + 1)   (exponentials precomputed in K1:
//     exp(2s) = EA*EB — no transcendental exp in the hot loop, only rcp).
// Block = 256 thr = 4 waves (d-quarters) x [2 i-rows x 64 j]. Grid (192,6) =
// 1152 blocks -> 4.5 waves/SIMD. EA-pair + W2 staged in LDS (rows padded to
// 12 floats, conflict-free broadcast b128). lane -> j, EB coalesced.
// Quarter-partials combined via LDS.
// ---------------------------------------------------------------------------
__global__ __launch_bounds__(256) void k2_fused(
    const float* __restrict__ ws, const float* __restrict__ W2,
    const float* __restrict__ b2, float* __restrict__ out) {
  __shared__ float As[192][12];    // [dg][row 0..1][d 0..3], cols 8..11 pad
  __shared__ float Wsh[192][12];   // [dg][c 0..1][d 0..3],  cols 8..11 pad
  __shared__ float part[3][2][64][2];

  const int lane = threadIdx.x & 63;
  const int h    = threadIdx.x >> 6;        // d-quarter 0..3
  const int i0   = blockIdx.x * 2;
  const int j    = blockIdx.y * 64 + lane;

  // stage EA-row pair + W2 into LDS (coalesced float4 source reads)
  for (int u = threadIdx.x; u < 768; u += 256) {
    if (u < 384) {
      const int row = u / 192, dg = u % 192;
      *(float4*)&As[dg][row * 4] =
          *(const float4*)&ws[(size_t)(i0 + row) * DDIM + dg * 4];
    } else {
      const int v = u - 384, c = v / 192, dg = v % 192;
      *(float4*)&Wsh[dg][c * 4] =
          *(const float4*)&W2[(size_t)c * DDIM + dg * 4];
    }
  }

  // quarter-range sumW (wave-uniform after butterfly)
  const float* __restrict__ w0g = W2 + h * 192;
  const float* __restrict__ w1g = W2 + DDIM + h * 192;
  float sw0 = w0g[lane] + w0g[lane + 64] + w0g[lane + 128];
  float sw1 = w1g[lane] + w1g[lane + 64] + w1g[lane + 128];
  #pragma unroll
  for (int off = 32; off; off >>= 1) {
    sw0 += __shfl_xor(sw0, off);
    sw1 += __shfl_xor(sw1, off);
  }
  __syncthreads();

  const float4* __restrict__ B4 =
      (const float4*)(ws + WS_BT) + (size_t)(h * 48) * NROWS + j;

  f32x4 s00 = {0,0,0,0}, s01 = {0,0,0,0};   // row0: c0, c1
  f32x4 s10 = {0,0,0,0}, s11 = {0,0,0,0};   // row1: c0, c1

  #pragma unroll 2
  for (int dg = 0; dg < 48; ++dg) {
    const int dgg = h * 48 + dg;
    const float4 b4  = B4[(size_t)dg * NROWS];         // coalesced per-lane (EB)
    const float4 av0 = *(const float4*)&As[dgg][0];    // LDS broadcast (EA)
    const float4 av1 = *(const float4*)&As[dgg][4];
    const float4 w04 = *(const float4*)&Wsh[dgg][0];
    const float4 w14 = *(const float4*)&Wsh[dgg][4];

    float r;
    r = __builtin_amdgcn_rcpf(fmaf(av0.x, b4.x, 1.f));
    s00[0] = fmaf(w04.x, r, s00[0]); s01[0] = fmaf(w14.x, r, s01[0]);
    r = __builtin_amdgcn_rcpf(fmaf(av1.x, b4.x, 1.f));
    s10[0] = fmaf(w04.x, r, s10[0]); s11[0] = fmaf(w14.x, r, s11[0]);

    r = __builtin_amdgcn_rcpf(fmaf(av0.y, b4.y, 1.f));
    s00[1] = fmaf(w04.y, r, s00[1]); s01[1] = fmaf(w14.y, r, s01[1]);
    r = __builtin_amdgcn_rcpf(fmaf(av1.y, b4.y, 1.f));
    s10[1] = fmaf(w04.y, r, s10[1]); s11[1] = fmaf(w14.y, r, s11[1]);

    r = __builtin_amdgcn_rcpf(fmaf(av0.z, b4.z, 1.f));
    s00[2] = fmaf(w04.z, r, s00[2]); s01[2] = fmaf(w14.z, r, s01[2]);
    r = __builtin_amdgcn_rcpf(fmaf(av1.z, b4.z, 1.f));
    s10[2] = fmaf(w04.z, r, s10[2]); s11[2] = fmaf(w14.z, r, s11[2]);

    r = __builtin_amdgcn_rcpf(fmaf(av0.w, b4.w, 1.f));
    s00[3] = fmaf(w04.w, r, s00[3]); s01[3] = fmaf(w14.w, r, s01[3]);
    r = __builtin_amdgcn_rcpf(fmaf(av1.w, b4.w, 1.f));
    s10[3] = fmaf(w04.w, r, s10[3]); s11[3] = fmaf(w14.w, r, s11[3]);
  }

  const float S00 = (s00[0] + s00[1]) + (s00[2] + s00[3]);
  const float S01 = (s01[0] + s01[1]) + (s01[2] + s01[3]);
  const float S10 = (s10[0] + s10[1]) + (s10[2] + s10[3]);
  const float S11 = (s11[0] + s11[1]) + (s11[2] + s11[3]);
  const float p00 = fmaf(-2.f, S00, sw0);
  const float p01 = fmaf(-2.f, S01, sw1);
  const float p10 = fmaf(-2.f, S10, sw0);
  const float p11 = fmaf(-2.f, S11, sw1);

  if (h) {
    part[h - 1][0][lane][0] = p00; part[h - 1][0][lane][1] = p01;
    part[h - 1][1][lane][0] = p10; part[h - 1][1][lane][1] = p11;
  }
  __syncthreads();
  if (!h) {
    float2 r0, r1;
    r0.x = p00 + part[0][0][lane][0] + part[1][0][lane][0] + part[2][0][lane][0] + b2[0];
    r0.y = p01 + part[0][0][lane][1] + part[1][0][lane][1] + part[2][0][lane][1] + b2[1];
    r1.x = p10 + part[0][1][lane][0] + part[1][1][lane][0] + part[2][1][lane][0] + b2[0];
    r1.y = p11 + part[0][1][lane][1] + part[1][1][lane][1] + part[2][1][lane][1] + b2[1];
    *(float2*)&out[((size_t)i0 * NROWS + j) * 2] = r0;
    *(float2*)&out[((size_t)(i0 + 1) * NROWS + j) * 2] = r1;
  }
}

// ---------------------------------------------------------------------------
extern "C" void kernel_launch(void* const* d_in, const int* in_sizes, int n_in,
                              void* d_out, int out_size, void* d_ws, size_t ws_size,
                              hipStream_t stream) {
  const float* p  = (const float*)d_in[0];   // [384, 768]
  const float* W1 = (const float*)d_in[1];   // [768, 1536]
  const float* b1 = (const float*)d_in[2];   // [768]
  const float* W2 = (const float*)d_in[3];   // [2, 768]
  const float* b2 = (const float*)d_in[4];   // [2]
  float* out = (float*)d_out;                // [384, 384, 2]
  float* ws  = (float*)d_ws;                 // ~5.3 MB used

  k0_cvt<<<dim3(720), 256, 0, stream>>>(p, W1, ws);

  dim3 g1(NCOL / 32, NROWS / 16);            // 48 x 24 = 1152 blocks
  k1_mfma<<<g1, 256, 0, stream>>>(b1, ws);

  dim3 g2(NROWS / 2, NROWS / 64);            // 192 x 6 = 1152 blocks
  k2_fused<<<g2, 256, 0, stream>>>(ws, W2, b2, out);
}